// Round 1
// baseline (381.196 us; speedup 1.0000x reference)
//
#include <hip/hip_runtime.h>
#include <math.h>

// Problem constants (fixed by setup_inputs: B=64, C=1, H=512, W=512 fp32)
static constexpr int Hdim = 512;
static constexpr int Wdim = 512;
static constexpr int HW   = Hdim * Wdim;   // 2^18

// d_ws accumulators: [0]=sum focal, [1]=sum p*t, [2]=sum p, [3]=sum t, [4]=sum bce*weight
__global__ void zero_ws_kernel(double* ws) {
    if (threadIdx.x < 5) ws[threadIdx.x] = 0.0;
}

__global__ __launch_bounds__(256) void combined_loss_kernel(
    const float* __restrict__ inp, const float* __restrict__ tgt,
    double* __restrict__ acc, int N)
{
    float s_focal = 0.f, s_inter = 0.f, s_p = 0.f, s_t = 0.f, s_bw = 0.f;
    const int stride = gridDim.x * blockDim.x;
    for (int i = blockIdx.x * blockDim.x + threadIdx.x; i < N; i += stride) {
        float xi = inp[i];
        float ti = tgt[i];
        float ax = fabsf(xi);
        float e  = __expf(-ax);                       // exp(-|x|)
        float bce = fmaxf(xi, 0.f) - xi * ti + log1pf(e);
        // sigmoid via e: x>=0 -> 1/(1+e), x<0 -> e/(1+e)
        float rden = __builtin_amdgcn_rcpf(1.f + e);
        float p = (xi >= 0.f ? 1.f : e) * rden;
        // pt = exp(-bce) == (t==1 ? p : 1-p) exactly (t is 0/1)
        bool tpos = ti > 0.5f;
        float pt = tpos ? p : 1.f - p;
        float om = 1.f - pt;
        s_focal += 0.25f * om * om * bce;
        s_p     += p;
        s_t     += ti;
        s_inter += p * ti;

        // boundary: radius-2 L1 diamond erosion & dilation of (t > 0.5), OOB = false
        int xy = i & (HW - 1);
        int yy = xy >> 9;          // / 512
        int xx = xy & (Wdim - 1);  // % 512
        const float* tb = tgt + (i - xy);   // base of this image
        bool er = tpos, di = tpos;
        #define MORPH(dy, dx) do {                                             \
            int ny = yy + (dy), nx = xx + (dx);                                \
            bool inb = (unsigned)ny < (unsigned)Hdim && (unsigned)nx < (unsigned)Wdim; \
            bool v = inb && (tb[(ny << 9) + nx] > 0.5f);                       \
            er = er && v; di = di || v; } while (0)
        MORPH( 0,  1); MORPH( 0, -1); MORPH( 1,  0); MORPH(-1,  0);
        MORPH( 0,  2); MORPH( 0, -2); MORPH( 2,  0); MORPH(-2,  0);
        MORPH( 1,  1); MORPH( 1, -1); MORPH(-1,  1); MORPH(-1, -1);
        #undef MORPH
        bool boundary = di && !er;
        float wgt = boundary ? 6.0f : 1.0f;   // 1 + THETA*boundary
        s_bw += bce * wgt;
    }

    // wave (64-lane) shuffle reduction
    #pragma unroll
    for (int off = 32; off > 0; off >>= 1) {
        s_focal += __shfl_down(s_focal, off);
        s_inter += __shfl_down(s_inter, off);
        s_p     += __shfl_down(s_p,     off);
        s_t     += __shfl_down(s_t,     off);
        s_bw    += __shfl_down(s_bw,    off);
    }
    __shared__ float smem[4][5];
    int wave = threadIdx.x >> 6;
    int lane = threadIdx.x & 63;
    if (lane == 0) {
        smem[wave][0] = s_focal; smem[wave][1] = s_inter; smem[wave][2] = s_p;
        smem[wave][3] = s_t;     smem[wave][4] = s_bw;
    }
    __syncthreads();
    if (threadIdx.x == 0) {
        double a0 = 0, a1 = 0, a2 = 0, a3 = 0, a4 = 0;
        #pragma unroll
        for (int w = 0; w < 4; w++) {
            a0 += smem[w][0]; a1 += smem[w][1]; a2 += smem[w][2];
            a3 += smem[w][3]; a4 += smem[w][4];
        }
        atomicAdd(&acc[0], a0);
        atomicAdd(&acc[1], a1);
        atomicAdd(&acc[2], a2);
        atomicAdd(&acc[3], a3);
        atomicAdd(&acc[4], a4);
    }
}

__global__ void finalize_kernel(const double* __restrict__ acc, float* __restrict__ out, int N) {
    double invN = 1.0 / (double)N;
    double focal_loss = acc[0] * invN;
    double dice = (2.0 * acc[1] + 1e-6) / (acc[2] + acc[3] + 1e-6);
    double dice_loss = 1.0 - dice;
    double boundary_loss = acc[4] * invN;
    out[0] = (float)(0.3 * focal_loss + 0.4 * dice_loss + 0.3 * boundary_loss);
}

extern "C" void kernel_launch(void* const* d_in, const int* in_sizes, int n_in,
                              void* d_out, int out_size, void* d_ws, size_t ws_size,
                              hipStream_t stream) {
    const float* inp = (const float*)d_in[0];
    const float* tgt = (const float*)d_in[1];
    float* out = (float*)d_out;
    double* acc = (double*)d_ws;
    int N = in_sizes[0];   // 16,777,216

    zero_ws_kernel<<<1, 64, 0, stream>>>(acc);
    combined_loss_kernel<<<2048, 256, 0, stream>>>(inp, tgt, acc, N);
    finalize_kernel<<<1, 1, 0, stream>>>(acc, out, N);
}

// Round 2
// 239.542 us; speedup vs baseline: 1.5914x; 1.5914x over previous
//
#include <hip/hip_runtime.h>
#include <math.h>

// Problem constants (fixed by setup_inputs: B=64, C=1, H=512, W=512 fp32)
static constexpr int Hdim = 512;
static constexpr int Wdim = 512;
static constexpr int HW   = Hdim * Wdim;       // 2^18 px per image
static constexpr int RSTRIP = 32;              // rows per block strip
static constexpr int NBLK = 64 * (Hdim / RSTRIP);  // 1024 blocks
static constexpr int WPR = Wdim / 64;          // 8 uint64 words per row

// d_ws: [0..4] double accumulators (focal, inter, sum_p, sum_t, bce*w), [5] ticket counter
__global__ void zero_ws_kernel(double* ws) {
    if (threadIdx.x < 6) ws[threadIdx.x] = 0.0;
}

__device__ __forceinline__ unsigned long long shl1(unsigned long long c, unsigned long long l) {
    return (c << 1) | (l >> 63);   // value at x-1
}
__device__ __forceinline__ unsigned long long shr1(unsigned long long c, unsigned long long r) {
    return (c >> 1) | (r << 63);   // value at x+1
}
__device__ __forceinline__ unsigned long long shl2(unsigned long long c, unsigned long long l) {
    return (c << 2) | (l >> 62);
}
__device__ __forceinline__ unsigned long long shr2(unsigned long long c, unsigned long long r) {
    return (c >> 2) | (r << 62);
}

__global__ __launch_bounds__(256) void combined_loss_kernel(
    const float* __restrict__ inp, const float* __restrict__ tgt,
    double* __restrict__ acc, float* __restrict__ out)
{
    __shared__ unsigned long long tmask[RSTRIP + 4][WPR];  // rows r0-2 .. r0+RSTRIP+1
    __shared__ unsigned long long bmask[RSTRIP][WPR];      // boundary bits for strip rows
    __shared__ float smem[4][5];

    const int img   = blockIdx.x / (Hdim / RSTRIP);
    const int strip = blockIdx.x % (Hdim / RSTRIP);
    const int r0    = strip * RSTRIP;
    const float* tb = tgt + img * HW;
    const float* ib = inp + img * HW;

    const int wave = threadIdx.x >> 6;
    const int lane = threadIdx.x & 63;

    // ---- Phase 1: build target bitmask rows [r0-2, r0+RSTRIP+2) via ballot ----
    for (int pair = wave; pair < (RSTRIP + 4) * WPR; pair += 4) {
        int row  = pair >> 3;          // 0..35 (mask row)
        int word = pair & 7;
        int gr   = r0 - 2 + row;       // global row
        float v = 0.f;
        if ((unsigned)gr < (unsigned)Hdim)       // wave-uniform branch
            v = tb[gr * Wdim + word * 64 + lane];
        unsigned long long m = __ballot(v > 0.5f);
        if (lane == 0) tmask[row][word] = m;
    }
    __syncthreads();

    // ---- Phase 2: boundary = dilate2 & ~erode2 (radius-2 L1 diamond), bitwise ----
    {
        int tid = threadIdx.x;          // 256 threads -> 32 rows x 8 words
        int row  = tid >> 3;            // strip row 0..31
        int word = tid & 7;
        int mr = row + 2;               // center mask row

        #define CW(r)  tmask[r][word]
        #define LW(r)  (word > 0 ? tmask[r][word - 1] : 0ULL)
        #define RW(r)  (word < WPR - 1 ? tmask[r][word + 1] : 0ULL)

        unsigned long long c0 = CW(mr),   l0 = LW(mr),   rr0 = RW(mr);
        unsigned long long cm = CW(mr-1), lm = LW(mr-1), rm  = RW(mr-1);
        unsigned long long cp = CW(mr+1), lp = LW(mr+1), rp  = RW(mr+1);
        unsigned long long cm2 = CW(mr-2);
        unsigned long long cp2 = CW(mr+2);
        #undef CW
        #undef LW
        #undef RW

        unsigned long long er =
            c0 & shl1(c0,l0) & shr1(c0,rr0) & shl2(c0,l0) & shr2(c0,rr0)
               & cm & shl1(cm,lm) & shr1(cm,rm)
               & cp & shl1(cp,lp) & shr1(cp,rp)
               & cm2 & cp2;
        unsigned long long di =
            c0 | shl1(c0,l0) | shr1(c0,rr0) | shl2(c0,l0) | shr2(c0,rr0)
               | cm | shl1(cm,lm) | shr1(cm,rm)
               | cp | shl1(cp,lp) | shr1(cp,rp)
               | cm2 | cp2;
        bmask[row][word] = di & ~er;
    }
    __syncthreads();

    // ---- Phase 3: elementwise math, float4 over the strip ----
    float s_focal = 0.f, s_inter = 0.f, s_p = 0.f, s_t = 0.f, s_bw = 0.f;
    #pragma unroll
    for (int it = 0; it < (RSTRIP * Wdim) / (256 * 4); it++) {
        int flat = it * 1024 + threadIdx.x * 4;   // px within strip
        int row  = flat >> 9;                     // 0..31
        int x    = flat & (Wdim - 1);             // multiple of 4
        const float4 f4 = *(const float4*)(ib + (r0 + row) * Wdim + x);
        unsigned int tb4 = (unsigned int)((tmask[row + 2][x >> 6] >> (x & 63)) & 0xFULL);
        unsigned int bb4 = (unsigned int)((bmask[row][x >> 6]     >> (x & 63)) & 0xFULL);
        const float xs[4] = {f4.x, f4.y, f4.z, f4.w};
        #pragma unroll
        for (int k = 0; k < 4; k++) {
            float xi = xs[k];
            bool tpos = (tb4 >> k) & 1;
            float ti = tpos ? 1.f : 0.f;
            float e  = __expf(-fabsf(xi));                  // exp(-|x|)
            float bce = fmaxf(xi, 0.f) - xi * ti + __logf(1.f + e);
            float rden = __builtin_amdgcn_rcpf(1.f + e);
            float p = (xi >= 0.f ? 1.f : e) * rden;         // sigmoid
            float pt = tpos ? p : 1.f - p;                  // == exp(-bce)
            float om = 1.f - pt;
            s_focal += 0.25f * om * om * bce;
            s_p     += p;
            s_t     += ti;
            s_inter += tpos ? p : 0.f;
            float wgt = ((bb4 >> k) & 1) ? 6.0f : 1.0f;     // 1 + THETA*boundary
            s_bw += bce * wgt;
        }
    }

    // ---- Reduce: wave shuffle -> LDS -> block atomics ----
    #pragma unroll
    for (int off = 32; off > 0; off >>= 1) {
        s_focal += __shfl_down(s_focal, off);
        s_inter += __shfl_down(s_inter, off);
        s_p     += __shfl_down(s_p,     off);
        s_t     += __shfl_down(s_t,     off);
        s_bw    += __shfl_down(s_bw,    off);
    }
    if (lane == 0) {
        smem[wave][0] = s_focal; smem[wave][1] = s_inter; smem[wave][2] = s_p;
        smem[wave][3] = s_t;     smem[wave][4] = s_bw;
    }
    __syncthreads();
    if (threadIdx.x == 0) {
        double a0 = 0, a1 = 0, a2 = 0, a3 = 0, a4 = 0;
        #pragma unroll
        for (int w = 0; w < 4; w++) {
            a0 += smem[w][0]; a1 += smem[w][1]; a2 += smem[w][2];
            a3 += smem[w][3]; a4 += smem[w][4];
        }
        atomicAdd(&acc[0], a0);
        atomicAdd(&acc[1], a1);
        atomicAdd(&acc[2], a2);
        atomicAdd(&acc[3], a3);
        atomicAdd(&acc[4], a4);
        __threadfence();
        unsigned long long ticket =
            atomicAdd((unsigned long long*)&acc[5], 1ULL);
        if (ticket == (unsigned long long)(gridDim.x - 1)) {
            // last block: all prior atomics are device-visible (fence+atomic order)
            double b0 = atomicAdd(&acc[0], 0.0);
            double b1 = atomicAdd(&acc[1], 0.0);
            double b2 = atomicAdd(&acc[2], 0.0);
            double b3 = atomicAdd(&acc[3], 0.0);
            double b4 = atomicAdd(&acc[4], 0.0);
            double invN = 1.0 / (double)(64 * HW);
            double focal_loss = b0 * invN;
            double dice = (2.0 * b1 + 1e-6) / (b2 + b3 + 1e-6);
            double boundary_loss = b4 * invN;
            out[0] = (float)(0.3 * focal_loss + 0.4 * (1.0 - dice) + 0.3 * boundary_loss);
        }
    }
}

extern "C" void kernel_launch(void* const* d_in, const int* in_sizes, int n_in,
                              void* d_out, int out_size, void* d_ws, size_t ws_size,
                              hipStream_t stream) {
    const float* inp = (const float*)d_in[0];
    const float* tgt = (const float*)d_in[1];
    float* out = (float*)d_out;
    double* acc = (double*)d_ws;

    zero_ws_kernel<<<1, 64, 0, stream>>>(acc);
    combined_loss_kernel<<<NBLK, 256, 0, stream>>>(inp, tgt, acc, out);
}